// Round 11
// baseline (25857.263 us; speedup 1.0000x reference)
//
#include <hip/hip_runtime.h>
#include <hip/hip_bf16.h>
#include <stdint.h>

#define NB 256   // batch
#define NT 512   // time
#define NV 128   // vocab
#define NE 64    // embed
#define NH 256   // hidden

typedef __fp16 h2t __attribute__((ext_vector_type(2)));

// ---------------- helpers ----------------
__device__ __forceinline__ float lo_bf(unsigned u){ return __uint_as_float(u << 16); }
__device__ __forceinline__ float hi_bf(unsigned u){ return __uint_as_float(u & 0xffff0000u); }
__device__ __forceinline__ unsigned short f2us(float f){
  unsigned u = __float_as_uint(f);
  unsigned r = u + 0x7fffu + ((u >> 16) & 1u);
  return (unsigned short)(r >> 16);
}
__device__ __forceinline__ float sigm(float x){
  return __builtin_amdgcn_rcpf(1.f + __expf(-x));
}
__device__ __forceinline__ float ftanh(float xx){
  float a = fabsf(xx);
  a = fminf(a, 9.f);
  float e = __expf(2.f * a);
  float r = __builtin_amdgcn_rcpf(e + 1.f);
  float t = (e - 1.f) * r;
  return copysignf(t, xx);
}
__device__ __forceinline__ unsigned pkf16(float a, float b){
  h2t h = __builtin_amdgcn_cvt_pkrtz(a, b);
  unsigned u; __builtin_memcpy(&u, &h, 4); return u;
}
__device__ __forceinline__ float fdot2(unsigned a, unsigned b, float c){
#if __has_builtin(__builtin_amdgcn_fdot2)
  h2t A, B; __builtin_memcpy(&A, &a, 4); __builtin_memcpy(&B, &b, 4);
  return __builtin_amdgcn_fdot2(A, B, c, false);
#else
  h2t A, B; __builtin_memcpy(&A, &a, 4); __builtin_memcpy(&B, &b, 4);
  return c + (float)A.x*(float)B.x + (float)A.y*(float)B.y;
#endif
}

// ---------------- prep: pack all GEMV weights to f16-pair, k-major ----------------
__global__ __launch_bounds__(256, 1)
void prep_kernel(const float* __restrict__ Wq, const float* __restrict__ Wfc,
                 const float* __restrict__ Wihd, const float* __restrict__ Whhd,
                 const float* __restrict__ Wihe, const float* __restrict__ Whhe,
                 const float* __restrict__ Wk,
                 unsigned* __restrict__ Wq4, unsigned* __restrict__ Wfc4,
                 unsigned* __restrict__ Wihd4, unsigned* __restrict__ Whhd4,
                 unsigned* __restrict__ Wihe4, unsigned* __restrict__ Whhe4,
                 unsigned* __restrict__ Wke4)
{
  const int blk = blockIdx.x, tid = threadIdx.x;
  if (blk < 64){                        // Wq4: C=256, K=256 -> 64 k2p x 512
    int k2p = blk;
    #pragma unroll
    for (int l = 0; l < 2; ++l){
      int i = l*256 + tid, c = i>>1, j = i&1, k = 4*k2p + 2*j;
      Wq4[k2p*512 + i] = pkf16(Wq[c*256 + k], Wq[c*256 + k + 1]);
    }
  } else if (blk < 128){                // Wfc4: C=128, K=256 -> 64 k2p x 256
    int k2p = blk - 64;
    int c = tid>>1, j = tid&1, k = 4*k2p + 2*j;
    Wfc4[k2p*256 + tid] = pkf16(Wfc[c*256 + k], Wfc[c*256 + k + 1]);
  } else if (blk < 208){                // Wihd4: C=1024, K=320 -> 80 k2p x 2048
    int k2p = blk - 128;
    #pragma unroll
    for (int l = 0; l < 8; ++l){
      int i = l*256 + tid, g = i>>1, j = i&1, k = 4*k2p + 2*j;
      Wihd4[(size_t)k2p*2048 + i] = pkf16(Wihd[g*320 + k], Wihd[g*320 + k + 1]);
    }
  } else if (blk < 272){                // Whhd4: C=1024, K=256 -> 64 k2p x 2048
    int k2p = blk - 208;
    #pragma unroll
    for (int l = 0; l < 8; ++l){
      int i = l*256 + tid, g = i>>1, j = i&1, k = 4*k2p + 2*j;
      Whhd4[(size_t)k2p*2048 + i] = pkf16(Whhd[g*256 + k], Whhd[g*256 + k + 1]);
    }
  } else if (blk < 288){                // Wihe4: C=1024, K=64 -> 16 k2p x 2048
    int k2p = blk - 272;
    #pragma unroll
    for (int l = 0; l < 8; ++l){
      int i = l*256 + tid, g = i>>1, j = i&1, k = 4*k2p + 2*j;
      Wihe4[(size_t)k2p*2048 + i] = pkf16(Wihe[g*64 + k], Wihe[g*64 + k + 1]);
    }
  } else if (blk < 352){                // Whhe4: C=1024, K=256 -> 64 k2p x 2048
    int k2p = blk - 288;
    #pragma unroll
    for (int l = 0; l < 8; ++l){
      int i = l*256 + tid, g = i>>1, j = i&1, k = 4*k2p + 2*j;
      Whhe4[(size_t)k2p*2048 + i] = pkf16(Whhe[g*256 + k], Whhe[g*256 + k + 1]);
    }
  } else {                              // Wke4: C=256, K=256 -> 64 k2p x 512
    int k2p = blk - 352;
    #pragma unroll
    for (int l = 0; l < 2; ++l){
      int i = l*256 + tid, c = i>>1, j = i&1, k = 4*k2p + 2*j;
      Wke4[k2p*512 + i] = pkf16(Wk[c*256 + k], Wk[c*256 + k + 1]);
    }
  }
}

// ---------------- key transpose: keys_n[B][T][H] -> keys_t[B][H][T] ----------------
__global__ __launch_bounds__(256, 1)
void tr_kernel(const unsigned short* __restrict__ keys_n, unsigned short* __restrict__ keys_t)
{
  __shared__ unsigned short tile[64][68];
  const int blk = blockIdx.x, tid = threadIdx.x;
  const int b  = blk >> 5;
  const int tt = (blk >> 2) & 7;
  const int hh = blk & 3;
  const int t0 = tt*64, h0 = hh*64;

  #pragma unroll
  for (int i = 0; i < 4; ++i){
    int idx = tid + i*256;
    int t = idx >> 4, h4 = (idx & 15)*4;
    uint2 u = *(const uint2*)(keys_n + ((size_t)b*NT + t0 + t)*NH + h0 + h4);
    *(uint2*)&tile[t][h4] = u;
  }
  __syncthreads();
  #pragma unroll
  for (int i = 0; i < 4; ++i){
    int idx = tid + i*256;
    int h = idx >> 4, t4 = (idx & 15)*4;
    unsigned short a = tile[t4+0][h], bb = tile[t4+1][h], cc = tile[t4+2][h], dd = tile[t4+3][h];
    uint2 u; u.x = (unsigned)a | ((unsigned)bb << 16); u.y = (unsigned)cc | ((unsigned)dd << 16);
    *(uint2*)(keys_t + ((size_t)b*NH + h0 + h)*NT + t0 + t4) = u;
  }
}

// ---------------- encoder: 2 rows/WG, 1024 threads, dot2 GEMVs, WG-local ----------------
__global__ __launch_bounds__(1024, 1)
void enc_kernel(const int* __restrict__ x, const float* __restrict__ emb,
                const unsigned* __restrict__ Wihe4, const unsigned* __restrict__ Whhe4,
                const float* __restrict__ bih, const float* __restrict__ bhh,
                const unsigned* __restrict__ Wke4,
                unsigned short* __restrict__ enc_out, unsigned short* __restrict__ keys_n,
                float* __restrict__ g_h, float* __restrict__ g_c)
{
  const int tid = threadIdx.x;
  const int b0  = blockIdx.x * 2;

  __shared__ unsigned sH2[2][128];
  __shared__ unsigned sXe2[2][32];
  __shared__ float sG[2][1024];
  __shared__ float sBias[1024];
  __shared__ float sKP[1024];
  __shared__ uint8_t sXi[2][512];

  sBias[tid] = bih[tid] + bhh[tid];
  { int r = tid >> 9; sXi[r][tid & 511] = (uint8_t)x[(b0 + r)*NT + (tid & 511)]; }
  if (tid < 256) sH2[tid>>7][tid&127] = 0u;   // f16 pair (0,0)
  __syncthreads();
  if (tid < 64){
    int r = tid>>5, p = tid&31, idx = sXi[r][0];
    sXe2[r][p] = pkf16(emb[idx*NE + 2*p], emb[idx*NE + 2*p + 1]);
  }
  float creg = 0.f, hl = 0.f;
  __syncthreads();

  for (int t = 0; t < NT; ++t){
    // ===== B: gates (all 1024 threads, 1 gate x 2 rows) + key partials =====
    {
      const int g = tid;
      float a0 = sBias[g], a1 = a0;
      const unsigned* Wi = Wihe4 + g*2;
      #pragma unroll 4
      for (int p = 0; p < 16; ++p){
        uint2 w = *(const uint2*)(Wi + (size_t)p*2048);
        a0 = fdot2(sXe2[0][2*p], w.x, a0); a0 = fdot2(sXe2[0][2*p+1], w.y, a0);
        a1 = fdot2(sXe2[1][2*p], w.x, a1); a1 = fdot2(sXe2[1][2*p+1], w.y, a1);
      }
      const unsigned* Wh = Whhe4 + g*2;
      #pragma unroll 4
      for (int p = 0; p < 64; ++p){
        uint2 w = *(const uint2*)(Wh + (size_t)p*2048);
        a0 = fdot2(sH2[0][2*p], w.x, a0); a0 = fdot2(sH2[0][2*p+1], w.y, a0);
        a1 = fdot2(sH2[1][2*p], w.x, a1); a1 = fdot2(sH2[1][2*p+1], w.y, a1);
      }
      sG[0][g] = a0; sG[1][g] = a1;
    }
    if (t > 0){
      const int r = tid>>9, half = (tid>>8)&1, c = tid&255;
      float kp = 0.f;
      const unsigned* Wk4 = Wke4 + c*2;
      #pragma unroll 4
      for (int p = 0; p < 32; ++p){
        int k2p = half*32 + p;
        uint2 w = *(const uint2*)(Wk4 + k2p*512);
        kp = fdot2(sH2[r][2*k2p], w.x, kp);
        kp = fdot2(sH2[r][2*k2p+1], w.y, kp);
      }
      sKP[tid] = kp;
    }
    __syncthreads();
    // ===== C: cell (0-511) | keys combine+write (512-1023) =====
    if (tid < 512){
      const int r = tid>>8, cc = tid&255;
      float gi = sigm (sG[r][cc]);
      float gf = sigm (sG[r][256+cc]);
      float gg = ftanh(sG[r][512+cc]);
      float go = sigm (sG[r][768+cc]);
      float cn = gf*creg + gi*gg;
      float hn = go*ftanh(cn);
      creg = cn; hl = hn;
      enc_out[((size_t)(b0+r)*NT + t)*NH + cc] = f2us(hn);
      float hb = __shfl_down(hn, 1, 64);
      if (!(cc & 1)) sH2[r][cc>>1] = pkf16(hn, hb);
      if (tid < 64 && (t+1) < NT){
        int r2 = tid>>5, p = tid&31, idx = sXi[r2][t+1];
        sXe2[r2][p] = pkf16(emb[idx*NE + 2*p], emb[idx*NE + 2*p + 1]);
      }
    } else if (t > 0){
      const int r = (tid>>8)&1, c = tid&255;
      float kv = sKP[(r<<9) + c] + sKP[(r<<9) + 256 + c];
      keys_n[((size_t)(b0+r)*NT + (t-1))*NH + c] = f2us(kv);
    }
    __syncthreads();
  }
  // final keys[NT-1] from h_{NT-1}
  {
    const int r = tid>>9, half = (tid>>8)&1, c = tid&255;
    float kp = 0.f;
    const unsigned* Wk4 = Wke4 + c*2;
    #pragma unroll 4
    for (int p = 0; p < 32; ++p){
      int k2p = half*32 + p;
      uint2 w = *(const uint2*)(Wk4 + k2p*512);
      kp = fdot2(sH2[r][2*k2p], w.x, kp);
      kp = fdot2(sH2[r][2*k2p+1], w.y, kp);
    }
    sKP[tid] = kp;
  }
  __syncthreads();
  if (tid >= 512){
    const int r = (tid>>8)&1, c = tid&255;
    float kv = sKP[(r<<9) + c] + sKP[(r<<9) + 256 + c];
    keys_n[((size_t)(b0+r)*NT + (NT-1))*NH + c] = f2us(kv);
  } else {
    const int r = tid>>8, cc = tid&255;
    g_h[(b0+r)*NH + cc] = hl;
    g_c[(b0+r)*NH + cc] = creg;
  }
}

// ---------------- decoder: 1 row/WG, 1024 threads, wave-specialized overlap ----------------
// Waves 0-7: attention (energy->softmax->context). Waves 8-15: h-dependent gate
// partials (Whh + Wih-emb, 2 gates/thread) CONCURRENTLY. Then all 1024 finish
// the ctx-dependent gate part. Balanced LDS keys pin kept (12 LDS + 20 global rows/chunk).
__global__ __launch_bounds__(1024, 1)
void dec_kernel(const int* __restrict__ x, const float* __restrict__ emb,
                const unsigned* __restrict__ Wq4, const float* __restrict__ vvec,
                const unsigned* __restrict__ Wihd4, const unsigned* __restrict__ Whhd4,
                const float* __restrict__ bih, const float* __restrict__ bhh,
                const unsigned short* __restrict__ enc_out, const unsigned short* __restrict__ keys_t,
                const float* __restrict__ g_h, const float* __restrict__ g_c,
                unsigned* __restrict__ h2_hist, float* __restrict__ out_h, float* __restrict__ out_c)
{
  const int tid = threadIdx.x;
  const int b   = blockIdx.x;

  extern __shared__ unsigned short sKpin[];   // 96 k-rows x 512 t  (98304 B)

  __shared__ float sTMP[4096];
  __shared__ float sGP[1024];       // gate partials from waves 8-15
  __shared__ float sWp[512];
  __shared__ float sRed[8];
  __shared__ float sQ2[256];        // 2*log2(e) * q
  __shared__ unsigned sH2[128];
  __shared__ unsigned sCtx2[128];
  __shared__ unsigned sXe2[32];
  __shared__ float sG[1024];
  __shared__ float sBiasD[1024];
  __shared__ float sVm2[256];       // -2*v
  __shared__ float sVs[8];          // per-chunk sum of v (12 LDS + 20 global rows)
  __shared__ uint8_t sXi[512];

  sBiasD[tid] = bih[tid] + bhh[tid];
  if (tid < 256) sVm2[tid] = -2.f * vvec[tid];
  if (tid < 512) sXi[tid] = (uint8_t)x[b*NT + tid];
  if (tid < 128) sH2[tid] = pkf16(g_h[b*NH + 2*tid], g_h[b*NH + 2*tid + 1]);
  if (tid < 8){
    float s = 0.f;
    #pragma unroll
    for (int j = 0; j < 12; ++j) s += vvec[tid*12 + j];
    #pragma unroll
    for (int j = 0; j < 20; ++j) s += vvec[96 + tid*20 + j];
    sVs[tid] = s;
  }
  // pin keys k-rows 0..95 in LDS (96*512 bf16 = 24576 uints), coalesced
  {
    const unsigned* src = (const unsigned*)(keys_t + (size_t)b*NH*NT);
    unsigned* dst = (unsigned*)sKpin;
    #pragma unroll
    for (int i = 0; i < 24; ++i) dst[tid + i*1024] = src[tid + i*1024];
  }
  float creg = (tid < 256) ? g_c[b*NH + tid] : 0.f;
  float hl = 0.f;
  const float CLN = 2.885390081777927f;   // 2*log2(e)
  __syncthreads();

  for (int t = 0; t < NT; ++t){
    float ga0 = 0.f, ga1 = 0.f;       // gate partials (waves 8-15), live across B1/B2
    // ===== A: q-proj partials, 4 k-chunks x 256 cols (all threads) =====
    {
      const int c = tid & 255, kq = tid >> 8;
      float a = 0.f;
      const unsigned* Wp = Wq4 + c*2;
      #pragma unroll 4
      for (int p = 0; p < 16; ++p){
        int k2p = kq*16 + p;
        uint2 w = *(const uint2*)(Wp + k2p*512);
        a = fdot2(sH2[2*k2p], w.x, a);
        a = fdot2(sH2[2*k2p+1], w.y, a);
      }
      sTMP[kq*256 + c] = a;
    }
    __syncthreads();
    // ===== A2: combine q (pre-scaled), gather+pack emb_t =====
    if (tid < 256){
      float qv = sTMP[tid] + sTMP[256 + tid] + sTMP[512 + tid] + sTMP[768 + tid];
      sQ2[tid] = CLN * qv;
    } else if (tid < 288){
      int p = tid - 256, idx = sXi[t];
      sXe2[p] = pkf16(emb[idx*NE + 2*p], emb[idx*NE + 2*p + 1]);
    }
    __syncthreads();
    // ===== B1: energy partials (waves 0-7) | Whh gate partials 1 (waves 8-15) =====
    if (tid < 512){
      const int kh = tid >> 6, sp = tid & 63;     // 8 positions: sp*8..+7
      float e0 = sVs[kh], e1 = e0, e2 = e0, e3 = e0, e4 = e0, e5 = e0, e6 = e0, e7 = e0;
      const unsigned short* ktg = keys_t + ((size_t)b*NH + 96 + kh*20)*NT + sp*8;
      #pragma unroll 2
      for (int j = 0; j < 20; ++j){
        uint4 u = *(const uint4*)(ktg + (size_t)j*NT);
        int ka = 96 + kh*20 + j;
        float q2 = sQ2[ka], vm = sVm2[ka];
        e0 = fmaf(vm, __builtin_amdgcn_rcpf(1.f + exp2f(fmaf(CLN, lo_bf(u.x), q2))), e0);
        e1 = fmaf(vm, __builtin_amdgcn_rcpf(1.f + exp2f(fmaf(CLN, hi_bf(u.x), q2))), e1);
        e2 = fmaf(vm, __builtin_amdgcn_rcpf(1.f + exp2f(fmaf(CLN, lo_bf(u.y), q2))), e2);
        e3 = fmaf(vm, __builtin_amdgcn_rcpf(1.f + exp2f(fmaf(CLN, hi_bf(u.y), q2))), e3);
        e4 = fmaf(vm, __builtin_amdgcn_rcpf(1.f + exp2f(fmaf(CLN, lo_bf(u.z), q2))), e4);
        e5 = fmaf(vm, __builtin_amdgcn_rcpf(1.f + exp2f(fmaf(CLN, hi_bf(u.z), q2))), e5);
        e6 = fmaf(vm, __builtin_amdgcn_rcpf(1.f + exp2f(fmaf(CLN, lo_bf(u.w), q2))), e6);
        e7 = fmaf(vm, __builtin_amdgcn_rcpf(1.f + exp2f(fmaf(CLN, hi_bf(u.w), q2))), e7);
      }
      const unsigned short* ktl = sKpin + (size_t)(kh*12)*NT + sp*8;
      #pragma unroll 2
      for (int j = 0; j < 12; ++j){
        uint4 u = *(const uint4*)(ktl + (size_t)j*NT);
        int ka = kh*12 + j;
        float q2 = sQ2[ka], vm = sVm2[ka];
        e0 = fmaf(vm, __builtin_amdgcn_rcpf(1.f + exp2f(fmaf(CLN, lo_bf(u.x), q2))), e0);
        e1 = fmaf(vm, __builtin_amdgcn_rcpf(1.f + exp2f(fmaf(CLN, hi_bf(u.x), q2))), e1);
        e2 = fmaf(vm, __builtin_amdgcn_rcpf(1.f + exp2f(fmaf(CLN, lo_bf(u.y), q2))), e2);
        e3 = fmaf(vm, __builtin_amdgcn_rcpf(1.f + exp2f(fmaf(CLN, hi_bf(u.y), q2))), e3);
        e4 = fmaf(vm, __builtin_amdgcn_rcpf(1.f + exp2f(fmaf(CLN, lo_bf(u.z), q2))), e4);
        e5 = fmaf(vm, __builtin_amdgcn_rcpf(1.f + exp2f(fmaf(CLN, hi_bf(u.z), q2))), e5);
        e6 = fmaf(vm, __builtin_amdgcn_rcpf(1.f + exp2f(fmaf(CLN, lo_bf(u.w), q2))), e6);
        e7 = fmaf(vm, __builtin_amdgcn_rcpf(1.f + exp2f(fmaf(CLN, hi_bf(u.w), q2))), e7);
      }
      *(float4*)(sTMP + kh*512 + sp*8)     = make_float4(e0,e1,e2,e3);
      *(float4*)(sTMP + kh*512 + sp*8 + 4) = make_float4(e4,e5,e6,e7);
    } else {
      const int g4 = (tid - 512)*4;               // uint4 offset: gates 2l, 2l+1
      #pragma unroll 4
      for (int k2p = 0; k2p < 40; ++k2p){
        uint4 w = *(const uint4*)(Whhd4 + (size_t)k2p*2048 + g4);
        unsigned h0 = sH2[2*k2p], h1 = sH2[2*k2p+1];
        ga0 = fdot2(h0, w.x, ga0); ga0 = fdot2(h1, w.y, ga0);
        ga1 = fdot2(h0, w.z, ga1); ga1 = fdot2(h1, w.w, ga1);
      }
    }
    __syncthreads();
    // ===== B2: softmax combine (waves 0-7) | Whh tail + Wih-emb partials (waves 8-15) =====
    if (tid < 512){
      float e = sTMP[tid]      + sTMP[512+tid]  + sTMP[1024+tid] + sTMP[1536+tid]
              + sTMP[2048+tid] + sTMP[2560+tid] + sTMP[3072+tid] + sTMP[3584+tid];
      float w = (sXi[tid] == 0) ? 0.f : __expf(e);
      sWp[tid] = w;
      float s = w;
      #pragma unroll
      for (int off = 32; off > 0; off >>= 1) s += __shfl_down(s, off, 64);
      if ((tid & 63) == 0) sRed[tid >> 6] = s;
    } else {
      const int g4 = (tid - 512)*4;
      #pragma unroll 4
      for (int k2p = 40; k2p < 64; ++k2p){
        uint4 w = *(const uint4*)(Whhd4 + (size_t)k2p*2048 + g4);
        unsigned h0 = sH2[2*k2p], h1 = sH2[2*k2p+1];
        ga0 = fdot2(h0, w.x, ga0); ga0 = fdot2(h1, w.y, ga0);
        ga1 = fdot2(h0, w.z, ga1); ga1 = fdot2(h1, w.w, ga1);
      }
      #pragma unroll 4
      for (int k2p = 0; k2p < 16; ++k2p){
        uint4 w = *(const uint4*)(Wihd4 + (size_t)k2p*2048 + g4);
        unsigned x0 = sXe2[2*k2p], x1 = sXe2[2*k2p+1];
        ga0 = fdot2(x0, w.x, ga0); ga0 = fdot2(x1, w.y, ga0);
        ga1 = fdot2(x0, w.z, ga1); ga1 = fdot2(x1, w.w, ga1);
      }
      sGP[(tid-512)*2]     = ga0;
      sGP[(tid-512)*2 + 1] = ga1;
    }
    __syncthreads();
    // ===== B3: context partials (waves 0-7, 8 cols/thread) =====
    if (tid < 512){
      const int sc = tid >> 5;        // 16 s-chunks of 32
      const int kc = tid & 31;        // 8 cols: kc*8
      const unsigned short* ep = enc_out + ((size_t)b*NT + sc*32)*NH + kc*8;
      float a0=0.f,a1=0.f,a2=0.f,a3=0.f,a4=0.f,a5=0.f,a6=0.f,a7=0.f;
      #pragma unroll 4
      for (int ss = 0; ss < 32; ++ss){
        float w = sWp[sc*32 + ss];
        uint4 u = *(const uint4*)(ep + (size_t)ss*NH);
        a0 += w*lo_bf(u.x); a1 += w*hi_bf(u.x);
        a2 += w*lo_bf(u.y); a3 += w*hi_bf(u.y);
        a4 += w*lo_bf(u.z); a5 += w*hi_bf(u.z);
        a6 += w*lo_bf(u.w); a7 += w*hi_bf(u.w);
      }
      *(float4*)(sTMP + sc*256 + kc*8)     = make_float4(a0,a1,a2,a3);
      *(float4*)(sTMP + sc*256 + kc*8 + 4) = make_float4(a4,a5,a6,a7);
    }
    __syncthreads();
    // ===== B4: combine context + pack f16 pairs =====
    if (tid < 256){
      float den = sRed[0]+sRed[1]+sRed[2]+sRed[3]+sRed[4]+sRed[5]+sRed[6]+sRed[7];
      float rden = (den > 0.f) ? (1.f/den) : 0.f;
      float cs = 0.f;
      #pragma unroll
      for (int p = 0; p < 16; ++p) cs += sTMP[p*256 + tid];
      float cv = cs * rden;
      float cb = __shfl_down(cv, 1, 64);
      if (!(tid & 1)) sCtx2[tid>>1] = pkf16(cv, cb);
    }
    __syncthreads();
    // ===== C: ctx-dependent gate part (all 1024, 1 gate/thread) =====
    {
      const int g = tid;
      float a = sBiasD[g] + sGP[g];
      const unsigned* Wc = Wihd4 + g*2;
      #pragma unroll 4
      for (int k2p = 16; k2p < 80; ++k2p){
        uint2 w = *(const uint2*)(Wc + (size_t)k2p*2048);
        a = fdot2(sCtx2[2*(k2p-16)], w.x, a);
        a = fdot2(sCtx2[2*(k2p-16)+1], w.y, a);
      }
      sG[g] = a;
    }
    __syncthreads();
    // ===== S7: cell update + pack h + h-history dump =====
    if (tid < 256){
      float gi = sigm (sG[tid]);
      float gf = sigm (sG[256 + tid]);
      float gg = ftanh(sG[512 + tid]);
      float go = sigm (sG[768 + tid]);
      float cn = gf*creg + gi*gg;
      float hn = go*ftanh(cn);
      creg = cn; hl = hn;
      float hb = __shfl_down(hn, 1, 64);
      if (!(tid & 1)){
        unsigned hp = pkf16(hn, hb);
        sH2[tid>>1] = hp;
        h2_hist[((size_t)b*NT + t)*128 + (tid>>1)] = hp;
      }
    }
    __syncthreads();
  }

  if (tid < 256){
    out_h[b*NH + tid] = hl;
    out_c[b*NH + tid] = creg;
  }
}

// ---------------- fc: logits = h_hist @ Wfc^T + bfc  (8 rows per block) ----------------
__global__ __launch_bounds__(256, 1)
void fc_kernel(const unsigned* __restrict__ h2_hist, const unsigned* __restrict__ Wfc4,
               const float* __restrict__ bfc, float* __restrict__ logits)
{
  __shared__ unsigned sHH[1024];     // 8 rows x 128 pairs
  const int tid = threadIdx.x;
  const size_t row0 = (size_t)blockIdx.x * 8;
  #pragma unroll
  for (int l = 0; l < 4; ++l) sHH[l*256 + tid] = h2_hist[row0*128 + l*256 + tid];
  __syncthreads();
  const int r = tid >> 7, v = tid & 127;
  float bv = bfc[v];
  float a0 = bv, a1 = bv, a2 = bv, a3 = bv;
  const unsigned* Wp = Wfc4 + v*2;
  #pragma unroll 4
  for (int k2p = 0; k2p < 64; ++k2p){
    uint2 w = *(const uint2*)(Wp + k2p*256);
    int k2 = 2*k2p;
    a0 = fdot2(sHH[(r  )*128 + k2], w.x, a0); a0 = fdot2(sHH[(r  )*128 + k2+1], w.y, a0);
    a1 = fdot2(sHH[(r+2)*128 + k2], w.x, a1); a1 = fdot2(sHH[(r+2)*128 + k2+1], w.y, a1);
    a2 = fdot2(sHH[(r+4)*128 + k2], w.x, a2); a2 = fdot2(sHH[(r+4)*128 + k2+1], w.y, a2);
    a3 = fdot2(sHH[(r+6)*128 + k2], w.x, a3); a3 = fdot2(sHH[(r+6)*128 + k2+1], w.y, a3);
  }
  logits[(row0 + r    )*NV + v] = a0;
  logits[(row0 + r + 2)*NV + v] = a1;
  logits[(row0 + r + 4)*NV + v] = a2;
  logits[(row0 + r + 6)*NV + v] = a3;
}

// ---------------- launcher ----------------
extern "C" void kernel_launch(void* const* d_in, const int* in_sizes, int n_in,
                              void* d_out, int out_size, void* d_ws, size_t ws_size,
                              hipStream_t stream)
{
  (void)in_sizes; (void)n_in; (void)out_size; (void)ws_size;
  const int*   x    = (const int*)  d_in[0];
  const float* emb  = (const float*)d_in[1];
  const float* Wihe = (const float*)d_in[2];
  const float* Whhe = (const float*)d_in[3];
  const float* bihe = (const float*)d_in[4];
  const float* bhhe = (const float*)d_in[5];
  const float* Wq   = (const float*)d_in[6];
  const float* Wk   = (const float*)d_in[7];
  const float* vv   = (const float*)d_in[8];
  const float* Wihd = (const float*)d_in[9];
  const float* Whhd = (const float*)d_in[10];
  const float* bihd = (const float*)d_in[11];
  const float* bhhd = (const float*)d_in[12];
  const float* Wfc  = (const float*)d_in[13];
  const float* bfc  = (const float*)d_in[14];

  char* ws = (char*)d_ws;
  const size_t M64 = 67108864;
  unsigned short* enc   = (unsigned short*)(ws);           // 64 MB bf16 [B][T][H]
  unsigned short* keysn = (unsigned short*)(ws + M64);     // 64 MB bf16 [B][T][H]; later reused as h2_hist
  unsigned short* keyst = (unsigned short*)(ws + 2*M64);   // 64 MB bf16 [B][H][T]
  unsigned* h2_hist     = (unsigned*)(ws + M64);           // overlays keysn (dead after tr)
  float* g_h = (float*)(ws + 3*M64);                       // 256 KB
  float* g_c = g_h + NB*NH;
  unsigned* Wq4   = (unsigned*)(g_c + NB*NH);              // 64*512
  unsigned* Wfc4  = Wq4   + 64*512;                        // 64*256
  unsigned* Wihd4 = Wfc4  + 64*256;                        // 80*2048
  unsigned* Whhd4 = Wihd4 + 80*2048;                       // 64*2048
  unsigned* Wihe4 = Whhd4 + 64*2048;                       // 16*2048
  unsigned* Whhe4 = Wihe4 + 16*2048;                       // 64*2048
  unsigned* Wke4  = Whhe4 + 64*2048;                       // 64*512

  float* out_logits = (float*)d_out;
  float* out_h = out_logits + (size_t)NB*NT*NV;
  float* out_c = out_h + NB*NH;

  const int dynLds = 96 * 512 * 2;   // 98304 B pinned keys slice
  static int attrSet = 0;
  if (!attrSet){
    hipFuncSetAttribute(reinterpret_cast<const void*>(dec_kernel),
                        hipFuncAttributeMaxDynamicSharedMemorySize, dynLds);
    attrSet = 1;
  }

  prep_kernel<<<dim3(416), dim3(256), 0, stream>>>(
      Wq, Wfc, Wihd, Whhd, Wihe, Whhe, Wk,
      Wq4, Wfc4, Wihd4, Whhd4, Wihe4, Whhe4, Wke4);
  enc_kernel<<<dim3(128), dim3(1024), 0, stream>>>(
      x, emb, Wihe4, Whhe4, bihe, bhhe, Wke4, enc, keysn, g_h, g_c);
  tr_kernel<<<dim3(8192), dim3(256), 0, stream>>>(keysn, keyst);
  dec_kernel<<<dim3(256), dim3(1024), dynLds, stream>>>(
      x, emb, Wq4, vv, Wihd4, Whhd4, bihd, bhhd,
      enc, keyst, g_h, g_c, h2_hist, out_h, out_c);
  fc_kernel<<<dim3(16384), dim3(256), 0, stream>>>(h2_hist, Wfc4, bfc, out_logits);
}

// Round 12
// 25156.288 us; speedup vs baseline: 1.0279x; 1.0279x over previous
//
#include <hip/hip_runtime.h>
#include <hip/hip_bf16.h>
#include <stdint.h>

#define NB 256   // batch
#define NT 512   // time
#define NV 128   // vocab
#define NE 64    // embed
#define NH 256   // hidden

typedef __fp16 h2t __attribute__((ext_vector_type(2)));

// ---------------- helpers ----------------
__device__ __forceinline__ float lo_bf(unsigned u){ return __uint_as_float(u << 16); }
__device__ __forceinline__ float hi_bf(unsigned u){ return __uint_as_float(u & 0xffff0000u); }
__device__ __forceinline__ unsigned short f2us(float f){
  unsigned u = __float_as_uint(f);
  unsigned r = u + 0x7fffu + ((u >> 16) & 1u);
  return (unsigned short)(r >> 16);
}
__device__ __forceinline__ float sigm(float x){
  return __builtin_amdgcn_rcpf(1.f + __expf(-x));
}
__device__ __forceinline__ float ftanh(float xx){
  float a = fabsf(xx);
  a = fminf(a, 9.f);
  float e = __expf(2.f * a);
  float r = __builtin_amdgcn_rcpf(e + 1.f);
  float t = (e - 1.f) * r;
  return copysignf(t, xx);
}
__device__ __forceinline__ unsigned pkf16(float a, float b){
  h2t h = __builtin_amdgcn_cvt_pkrtz(a, b);
  unsigned u; __builtin_memcpy(&u, &h, 4); return u;
}
__device__ __forceinline__ float fdot2(unsigned a, unsigned b, float c){
#if __has_builtin(__builtin_amdgcn_fdot2)
  h2t A, B; __builtin_memcpy(&A, &a, 4); __builtin_memcpy(&B, &b, 4);
  return __builtin_amdgcn_fdot2(A, B, c, false);
#else
  h2t A, B; __builtin_memcpy(&A, &a, 4); __builtin_memcpy(&B, &b, 4);
  return c + (float)A.x*(float)B.x + (float)A.y*(float)B.y;
#endif
}

// ---------------- prep: pack all GEMV weights to f16-pair, k-major ----------------
__global__ __launch_bounds__(256, 1)
void prep_kernel(const float* __restrict__ Wq, const float* __restrict__ Wfc,
                 const float* __restrict__ Wihd, const float* __restrict__ Whhd,
                 const float* __restrict__ Wihe, const float* __restrict__ Whhe,
                 const float* __restrict__ Wk,
                 unsigned* __restrict__ Wq4, unsigned* __restrict__ Wfc4,
                 unsigned* __restrict__ Wihd4, unsigned* __restrict__ Whhd4,
                 unsigned* __restrict__ Wihe4, unsigned* __restrict__ Whhe4,
                 unsigned* __restrict__ Wke4)
{
  const int blk = blockIdx.x, tid = threadIdx.x;
  if (blk < 64){                        // Wq4: C=256, K=256 -> 64 k2p x 512
    int k2p = blk;
    #pragma unroll
    for (int l = 0; l < 2; ++l){
      int i = l*256 + tid, c = i>>1, j = i&1, k = 4*k2p + 2*j;
      Wq4[k2p*512 + i] = pkf16(Wq[c*256 + k], Wq[c*256 + k + 1]);
    }
  } else if (blk < 128){                // Wfc4: C=128, K=256 -> 64 k2p x 256
    int k2p = blk - 64;
    int c = tid>>1, j = tid&1, k = 4*k2p + 2*j;
    Wfc4[k2p*256 + tid] = pkf16(Wfc[c*256 + k], Wfc[c*256 + k + 1]);
  } else if (blk < 208){                // Wihd4: C=1024, K=320 -> 80 k2p x 2048
    int k2p = blk - 128;
    #pragma unroll
    for (int l = 0; l < 8; ++l){
      int i = l*256 + tid, g = i>>1, j = i&1, k = 4*k2p + 2*j;
      Wihd4[(size_t)k2p*2048 + i] = pkf16(Wihd[g*320 + k], Wihd[g*320 + k + 1]);
    }
  } else if (blk < 272){                // Whhd4: C=1024, K=256 -> 64 k2p x 2048
    int k2p = blk - 208;
    #pragma unroll
    for (int l = 0; l < 8; ++l){
      int i = l*256 + tid, g = i>>1, j = i&1, k = 4*k2p + 2*j;
      Whhd4[(size_t)k2p*2048 + i] = pkf16(Whhd[g*256 + k], Whhd[g*256 + k + 1]);
    }
  } else if (blk < 288){                // Wihe4: C=1024, K=64 -> 16 k2p x 2048
    int k2p = blk - 272;
    #pragma unroll
    for (int l = 0; l < 8; ++l){
      int i = l*256 + tid, g = i>>1, j = i&1, k = 4*k2p + 2*j;
      Wihe4[(size_t)k2p*2048 + i] = pkf16(Wihe[g*64 + k], Wihe[g*64 + k + 1]);
    }
  } else if (blk < 352){                // Whhe4: C=1024, K=256 -> 64 k2p x 2048
    int k2p = blk - 288;
    #pragma unroll
    for (int l = 0; l < 8; ++l){
      int i = l*256 + tid, g = i>>1, j = i&1, k = 4*k2p + 2*j;
      Whhe4[(size_t)k2p*2048 + i] = pkf16(Whhe[g*256 + k], Whhe[g*256 + k + 1]);
    }
  } else {                              // Wke4: C=256, K=256 -> 64 k2p x 512
    int k2p = blk - 352;
    #pragma unroll
    for (int l = 0; l < 2; ++l){
      int i = l*256 + tid, c = i>>1, j = i&1, k = 4*k2p + 2*j;
      Wke4[k2p*512 + i] = pkf16(Wk[c*256 + k], Wk[c*256 + k + 1]);
    }
  }
}

// ---------------- key transpose: keys_n[B][T][H] -> keys_t[B][H][T] ----------------
__global__ __launch_bounds__(256, 1)
void tr_kernel(const unsigned short* __restrict__ keys_n, unsigned short* __restrict__ keys_t)
{
  __shared__ unsigned short tile[64][68];
  const int blk = blockIdx.x, tid = threadIdx.x;
  const int b  = blk >> 5;
  const int tt = (blk >> 2) & 7;
  const int hh = blk & 3;
  const int t0 = tt*64, h0 = hh*64;

  #pragma unroll
  for (int i = 0; i < 4; ++i){
    int idx = tid + i*256;
    int t = idx >> 4, h4 = (idx & 15)*4;
    uint2 u = *(const uint2*)(keys_n + ((size_t)b*NT + t0 + t)*NH + h0 + h4);
    *(uint2*)&tile[t][h4] = u;
  }
  __syncthreads();
  #pragma unroll
  for (int i = 0; i < 4; ++i){
    int idx = tid + i*256;
    int h = idx >> 4, t4 = (idx & 15)*4;
    unsigned short a = tile[t4+0][h], bb = tile[t4+1][h], cc = tile[t4+2][h], dd = tile[t4+3][h];
    uint2 u; u.x = (unsigned)a | ((unsigned)bb << 16); u.y = (unsigned)cc | ((unsigned)dd << 16);
    *(uint2*)(keys_t + ((size_t)b*NH + h0 + h)*NT + t0 + t4) = u;
  }
}

// ---------------- encoder: ONE row/WG, 256 WGs, 1024 threads, h ping-pong ----------------
// Phase B: 1024 threads x 1 gate (160 dot2). Phase C: 0-255 cell, 256-511 full
// keys column for t-1 (reads old-h buffer), 512-543 emb prefetch. 2 barriers/step.
__global__ __launch_bounds__(1024, 1)
void enc_kernel(const int* __restrict__ x, const float* __restrict__ emb,
                const unsigned* __restrict__ Wihe4, const unsigned* __restrict__ Whhe4,
                const float* __restrict__ bih, const float* __restrict__ bhh,
                const unsigned* __restrict__ Wke4,
                unsigned short* __restrict__ enc_out, unsigned short* __restrict__ keys_n,
                float* __restrict__ g_h, float* __restrict__ g_c)
{
  const int tid = threadIdx.x;
  const int b   = blockIdx.x;

  __shared__ unsigned sH2[2][128];    // f16-pair h, ping-pong by t parity
  __shared__ unsigned sXe2[32];
  __shared__ float sG[1024];
  __shared__ float sBias[1024];
  __shared__ uint8_t sXi[512];

  sBias[tid] = bih[tid] + bhh[tid];
  if (tid < 512) sXi[tid] = (uint8_t)x[b*NT + tid];
  if (tid < 128){ sH2[0][tid] = 0u; sH2[1][tid] = 0u; }
  __syncthreads();
  if (tid < 32){
    int idx = sXi[0];
    sXe2[tid] = pkf16(emb[idx*NE + 2*tid], emb[idx*NE + 2*tid + 1]);
  }
  float creg = 0.f, hl = 0.f;
  __syncthreads();

  for (int t = 0; t < NT; ++t){
    const int cur = t & 1, nxt = cur ^ 1;
    // ===== B: gates — 1 gate per thread =====
    {
      const int g = tid;
      float a = sBias[g];
      const unsigned* Wi = Wihe4 + g*2;
      #pragma unroll 4
      for (int p = 0; p < 16; ++p){
        uint2 w = *(const uint2*)(Wi + (size_t)p*2048);
        a = fdot2(sXe2[2*p], w.x, a); a = fdot2(sXe2[2*p+1], w.y, a);
      }
      const unsigned* Wh = Whhe4 + g*2;
      #pragma unroll 4
      for (int p = 0; p < 64; ++p){
        uint2 w = *(const uint2*)(Wh + (size_t)p*2048);
        a = fdot2(sH2[cur][2*p], w.x, a); a = fdot2(sH2[cur][2*p+1], w.y, a);
      }
      sG[g] = a;
    }
    __syncthreads();
    // ===== C: cell (0-255) | keys[t-1] (256-511, reads OLD h) | emb t+1 (512-543) =====
    if (tid < 256){
      float gi = sigm (sG[tid]);
      float gf = sigm (sG[256 + tid]);
      float gg = ftanh(sG[512 + tid]);
      float go = sigm (sG[768 + tid]);
      float cn = gf*creg + gi*gg;
      float hn = go*ftanh(cn);
      creg = cn; hl = hn;
      enc_out[((size_t)b*NT + t)*NH + tid] = f2us(hn);
      float hb = __shfl_down(hn, 1, 64);
      if (!(tid & 1)) sH2[nxt][tid>>1] = pkf16(hn, hb);
    } else if (tid < 512){
      if (t > 0){
        const int c = tid - 256;
        float kp = 0.f;
        const unsigned* Wk4 = Wke4 + c*2;
        #pragma unroll 4
        for (int k2p = 0; k2p < 64; ++k2p){
          uint2 w = *(const uint2*)(Wk4 + k2p*512);
          kp = fdot2(sH2[cur][2*k2p], w.x, kp);
          kp = fdot2(sH2[cur][2*k2p+1], w.y, kp);
        }
        keys_n[((size_t)b*NT + (t-1))*NH + c] = f2us(kp);
      }
    } else if (tid < 544 && (t+1) < NT){
      int p = tid - 512, idx = sXi[t+1];
      sXe2[p] = pkf16(emb[idx*NE + 2*p], emb[idx*NE + 2*p + 1]);
    }
    __syncthreads();
  }

  // ===== final keys[NT-1] from h_511 (in buffer (NT)&1 = 0) + state handoff =====
  if (tid >= 256 && tid < 512){
    const int c = tid - 256;
    float kp = 0.f;
    const unsigned* Wk4 = Wke4 + c*2;
    #pragma unroll 4
    for (int k2p = 0; k2p < 64; ++k2p){
      uint2 w = *(const uint2*)(Wk4 + k2p*512);
      kp = fdot2(sH2[0][2*k2p], w.x, kp);
      kp = fdot2(sH2[0][2*k2p+1], w.y, kp);
    }
    keys_n[((size_t)b*NT + (NT-1))*NH + c] = f2us(kp);
  } else if (tid < 256){
    g_h[b*NH + tid] = hl;
    g_c[b*NH + tid] = creg;
  }
}

// ---------------- decoder: 1 row/WG, 1024 threads, BALANCED LDS keys pin (R10) ----------------
__global__ __launch_bounds__(1024, 1)
void dec_kernel(const int* __restrict__ x, const float* __restrict__ emb,
                const unsigned* __restrict__ Wq4, const float* __restrict__ vvec,
                const unsigned* __restrict__ Wihd4, const unsigned* __restrict__ Whhd4,
                const float* __restrict__ bih, const float* __restrict__ bhh,
                const unsigned short* __restrict__ enc_out, const unsigned short* __restrict__ keys_t,
                const float* __restrict__ g_h, const float* __restrict__ g_c,
                unsigned* __restrict__ h2_hist, float* __restrict__ out_h, float* __restrict__ out_c)
{
  const int tid = threadIdx.x;
  const int b   = blockIdx.x;

  extern __shared__ unsigned short sKpin[];   // 96 k-rows x 512 t  (98304 B)

  __shared__ float sTMP[4096];
  __shared__ float sWp[512];
  __shared__ float sRed[8];
  __shared__ float sQ2[256];        // 2*log2(e) * q
  __shared__ unsigned sH2[128];
  __shared__ unsigned sCtx2[128];
  __shared__ unsigned sXe2[32];
  __shared__ float sG[1024];
  __shared__ float sBiasD[1024];
  __shared__ float sVm2[256];       // -2*v
  __shared__ float sVs[8];          // per-chunk sum of v (12 LDS + 20 global rows)
  __shared__ uint8_t sXi[512];

  sBiasD[tid] = bih[tid] + bhh[tid];
  if (tid < 256) sVm2[tid] = -2.f * vvec[tid];
  if (tid < 512) sXi[tid] = (uint8_t)x[b*NT + tid];
  if (tid < 128) sH2[tid] = pkf16(g_h[b*NH + 2*tid], g_h[b*NH + 2*tid + 1]);
  if (tid < 8){
    float s = 0.f;
    #pragma unroll
    for (int j = 0; j < 12; ++j) s += vvec[tid*12 + j];
    #pragma unroll
    for (int j = 0; j < 20; ++j) s += vvec[96 + tid*20 + j];
    sVs[tid] = s;
  }
  // pin keys k-rows 0..95 in LDS (96*512 bf16 = 24576 uints), coalesced
  {
    const unsigned* src = (const unsigned*)(keys_t + (size_t)b*NH*NT);
    unsigned* dst = (unsigned*)sKpin;
    #pragma unroll
    for (int i = 0; i < 24; ++i) dst[tid + i*1024] = src[tid + i*1024];
  }
  float creg = (tid < 256) ? g_c[b*NH + tid] : 0.f;
  float hl = 0.f;
  const float CLN = 2.885390081777927f;   // 2*log2(e)
  __syncthreads();

  for (int t = 0; t < NT; ++t){
    // ===== S0: q-proj partials, 4 k-chunks x 256 cols =====
    {
      const int c = tid & 255, kq = tid >> 8;
      float a = 0.f;
      const unsigned* Wp = Wq4 + c*2;
      #pragma unroll 4
      for (int p = 0; p < 16; ++p){
        int k2p = kq*16 + p;
        uint2 w = *(const uint2*)(Wp + k2p*512);
        a = fdot2(sH2[2*k2p], w.x, a);
        a = fdot2(sH2[2*k2p+1], w.y, a);
      }
      sTMP[kq*256 + c] = a;
    }
    __syncthreads();
    // ===== S1: combine q (pre-scaled), gather+pack emb_t =====
    if (tid < 256){
      float qv = sTMP[tid] + sTMP[256 + tid] + sTMP[512 + tid] + sTMP[768 + tid];
      sQ2[tid] = CLN * qv;
    } else if (tid < 288){
      int p = tid - 256, idx = sXi[t];
      sXe2[p] = pkf16(emb[idx*NE + 2*p], emb[idx*NE + 2*p + 1]);
    }
    __syncthreads();
    // ===== S2: energy partials — mixed LDS(12 rows) + global(20 rows) per chunk =====
    {
      const int kh = tid >> 7, sp = tid & 127;
      float e0 = sVs[kh], e1 = e0, e2 = e0, e3 = e0;
      // global part first: issue loads early, 20 rows at k = 96 + kh*20 + j
      const unsigned short* ktg = keys_t + ((size_t)b*NH + 96 + kh*20)*NT + sp*4;
      #pragma unroll 4
      for (int j = 0; j < 20; ++j){
        uint2 u = *(const uint2*)(ktg + (size_t)j*NT);
        int ka = 96 + kh*20 + j;
        float q2 = sQ2[ka];
        float vm = sVm2[ka];
        float r0 = __builtin_amdgcn_rcpf(1.f + exp2f(fmaf(CLN, lo_bf(u.x), q2)));
        float r1 = __builtin_amdgcn_rcpf(1.f + exp2f(fmaf(CLN, hi_bf(u.x), q2)));
        float r2 = __builtin_amdgcn_rcpf(1.f + exp2f(fmaf(CLN, lo_bf(u.y), q2)));
        float r3 = __builtin_amdgcn_rcpf(1.f + exp2f(fmaf(CLN, hi_bf(u.y), q2)));
        e0 = fmaf(vm, r0, e0); e1 = fmaf(vm, r1, e1);
        e2 = fmaf(vm, r2, e2); e3 = fmaf(vm, r3, e3);
      }
      // LDS part: 12 rows at k = kh*12 + j
      const unsigned short* ktl = sKpin + (size_t)(kh*12)*NT + sp*4;
      #pragma unroll 4
      for (int j = 0; j < 12; ++j){
        uint2 u = *(const uint2*)(ktl + (size_t)j*NT);
        int ka = kh*12 + j;
        float q2 = sQ2[ka];
        float vm = sVm2[ka];
        float r0 = __builtin_amdgcn_rcpf(1.f + exp2f(fmaf(CLN, lo_bf(u.x), q2)));
        float r1 = __builtin_amdgcn_rcpf(1.f + exp2f(fmaf(CLN, hi_bf(u.x), q2)));
        float r2 = __builtin_amdgcn_rcpf(1.f + exp2f(fmaf(CLN, lo_bf(u.y), q2)));
        float r3 = __builtin_amdgcn_rcpf(1.f + exp2f(fmaf(CLN, hi_bf(u.y), q2)));
        e0 = fmaf(vm, r0, e0); e1 = fmaf(vm, r1, e1);
        e2 = fmaf(vm, r2, e2); e3 = fmaf(vm, r3, e3);
      }
      *(float4*)(sTMP + kh*512 + sp*4) = make_float4(e0,e1,e2,e3);
    }
    __syncthreads();
    // ===== S3: combine energies, mask, exp, per-wave denom partials =====
    if (tid < 512){
      float e = sTMP[tid]      + sTMP[512+tid]  + sTMP[1024+tid] + sTMP[1536+tid]
              + sTMP[2048+tid] + sTMP[2560+tid] + sTMP[3072+tid] + sTMP[3584+tid];
      float w = (sXi[tid] == 0) ? 0.f : __expf(e);
      sWp[tid] = w;
      float s = w;
      #pragma unroll
      for (int off = 32; off > 0; off >>= 1) s += __shfl_down(s, off, 64);
      if ((tid & 63) == 0) sRed[tid >> 6] = s;
    }
    __syncthreads();
    // ===== S4: context partials — enc_out[b][t][h] coalesced along H =====
    {
      const int sc = tid >> 6;
      const int kc = tid & 63;
      const unsigned short* ep = enc_out + ((size_t)b*NT + sc*32)*NH + kc*4;
      float a0=0.f, a1=0.f, a2=0.f, a3=0.f;
      #pragma unroll 8
      for (int ss = 0; ss < 32; ++ss){
        float w = sWp[sc*32 + ss];
        uint2 u = *(const uint2*)(ep + (size_t)ss*NH);
        a0 += w*lo_bf(u.x); a1 += w*hi_bf(u.x);
        a2 += w*lo_bf(u.y); a3 += w*hi_bf(u.y);
      }
      *(float4*)(sTMP + sc*256 + kc*4) = make_float4(a0,a1,a2,a3);
    }
    __syncthreads();
    // ===== S5: combine context + pack f16 pairs =====
    if (tid < 256){
      float den = sRed[0]+sRed[1]+sRed[2]+sRed[3]+sRed[4]+sRed[5]+sRed[6]+sRed[7];
      float rden = (den > 0.f) ? (1.f/den) : 0.f;
      float cs = 0.f;
      #pragma unroll
      for (int p = 0; p < 16; ++p) cs += sTMP[p*256 + tid];
      float cv = cs * rden;
      float cb = __shfl_down(cv, 1, 64);
      if (!(tid & 1)) sCtx2[tid>>1] = pkf16(cv, cb);
    }
    __syncthreads();
    // ===== S6: gates — 1 gate per thread, dot2, direct write =====
    {
      const int g = tid;
      float a = sBiasD[g];
      const unsigned* Wi = Wihd4 + g*2;
      #pragma unroll 4
      for (int p = 0; p < 16; ++p){
        uint2 w = *(const uint2*)(Wi + (size_t)p*2048);
        a = fdot2(sXe2[2*p], w.x, a); a = fdot2(sXe2[2*p+1], w.y, a);
      }
      #pragma unroll 4
      for (int p = 0; p < 64; ++p){
        uint2 w = *(const uint2*)(Wi + (size_t)(16+p)*2048);
        a = fdot2(sCtx2[2*p], w.x, a); a = fdot2(sCtx2[2*p+1], w.y, a);
      }
      const unsigned* Wh = Whhd4 + g*2;
      #pragma unroll 4
      for (int p = 0; p < 64; ++p){
        uint2 w = *(const uint2*)(Wh + (size_t)p*2048);
        a = fdot2(sH2[2*p], w.x, a); a = fdot2(sH2[2*p+1], w.y, a);
      }
      sG[g] = a;
    }
    __syncthreads();
    // ===== S7: cell update + pack h + h-history dump =====
    if (tid < 256){
      float gi = sigm (sG[tid]);
      float gf = sigm (sG[256 + tid]);
      float gg = ftanh(sG[512 + tid]);
      float go = sigm (sG[768 + tid]);
      float cn = gf*creg + gi*gg;
      float hn = go*ftanh(cn);
      creg = cn; hl = hn;
      float hb = __shfl_down(hn, 1, 64);
      if (!(tid & 1)){
        unsigned hp = pkf16(hn, hb);
        sH2[tid>>1] = hp;
        h2_hist[((size_t)b*NT + t)*128 + (tid>>1)] = hp;
      }
    }
    __syncthreads();
  }

  if (tid < 256){
    out_h[b*NH + tid] = hl;
    out_c[b*NH + tid] = creg;
  }
}

// ---------------- fc: logits = h_hist @ Wfc^T + bfc  (8 rows per block) ----------------
__global__ __launch_bounds__(256, 1)
void fc_kernel(const unsigned* __restrict__ h2_hist, const unsigned* __restrict__ Wfc4,
               const float* __restrict__ bfc, float* __restrict__ logits)
{
  __shared__ unsigned sHH[1024];     // 8 rows x 128 pairs
  const int tid = threadIdx.x;
  const size_t row0 = (size_t)blockIdx.x * 8;
  #pragma unroll
  for (int l = 0; l < 4; ++l) sHH[l*256 + tid] = h2_hist[row0*128 + l*256 + tid];
  __syncthreads();
  const int r = tid >> 7, v = tid & 127;
  float bv = bfc[v];
  float a0 = bv, a1 = bv, a2 = bv, a3 = bv;
  const unsigned* Wp = Wfc4 + v*2;
  #pragma unroll 4
  for (int k2p = 0; k2p < 64; ++k2p){
    uint2 w = *(const uint2*)(Wp + k2p*256);
    int k2 = 2*k2p;
    a0 = fdot2(sHH[(r  )*128 + k2], w.x, a0); a0 = fdot2(sHH[(r  )*128 + k2+1], w.y, a0);
    a1 = fdot2(sHH[(r+2)*128 + k2], w.x, a1); a1 = fdot2(sHH[(r+2)*128 + k2+1], w.y, a1);
    a2 = fdot2(sHH[(r+4)*128 + k2], w.x, a2); a2 = fdot2(sHH[(r+4)*128 + k2+1], w.y, a2);
    a3 = fdot2(sHH[(r+6)*128 + k2], w.x, a3); a3 = fdot2(sHH[(r+6)*128 + k2+1], w.y, a3);
  }
  logits[(row0 + r    )*NV + v] = a0;
  logits[(row0 + r + 2)*NV + v] = a1;
  logits[(row0 + r + 4)*NV + v] = a2;
  logits[(row0 + r + 6)*NV + v] = a3;
}

// ---------------- launcher ----------------
extern "C" void kernel_launch(void* const* d_in, const int* in_sizes, int n_in,
                              void* d_out, int out_size, void* d_ws, size_t ws_size,
                              hipStream_t stream)
{
  (void)in_sizes; (void)n_in; (void)out_size; (void)ws_size;
  const int*   x    = (const int*)  d_in[0];
  const float* emb  = (const float*)d_in[1];
  const float* Wihe = (const float*)d_in[2];
  const float* Whhe = (const float*)d_in[3];
  const float* bihe = (const float*)d_in[4];
  const float* bhhe = (const float*)d_in[5];
  const float* Wq   = (const float*)d_in[6];
  const float* Wk   = (const float*)d_in[7];
  const float* vv   = (const float*)d_in[8];
  const float* Wihd = (const float*)d_in[9];
  const float* Whhd = (const float*)d_in[10];
  const float* bihd = (const float*)d_in[11];
  const float* bhhd = (const float*)d_in[12];
  const float* Wfc  = (const float*)d_in[13];
  const float* bfc  = (const float*)d_in[14];

  char* ws = (char*)d_ws;
  const size_t M64 = 67108864;
  unsigned short* enc   = (unsigned short*)(ws);           // 64 MB bf16 [B][T][H]
  unsigned short* keysn = (unsigned short*)(ws + M64);     // 64 MB bf16 [B][T][H]; later reused as h2_hist
  unsigned short* keyst = (unsigned short*)(ws + 2*M64);   // 64 MB bf16 [B][H][T]
  unsigned* h2_hist     = (unsigned*)(ws + M64);           // overlays keysn (dead after tr)
  float* g_h = (float*)(ws + 3*M64);                       // 256 KB
  float* g_c = g_h + NB*NH;
  unsigned* Wq4   = (unsigned*)(g_c + NB*NH);              // 64*512
  unsigned* Wfc4  = Wq4   + 64*512;                        // 64*256
  unsigned* Wihd4 = Wfc4  + 64*256;                        // 80*2048
  unsigned* Whhd4 = Wihd4 + 80*2048;                       // 64*2048
  unsigned* Wihe4 = Whhd4 + 64*2048;                       // 16*2048
  unsigned* Whhe4 = Wihe4 + 16*2048;                       // 64*2048
  unsigned* Wke4  = Whhe4 + 64*2048;                       // 64*512

  float* out_logits = (float*)d_out;
  float* out_h = out_logits + (size_t)NB*NT*NV;
  float* out_c = out_h + NB*NH;

  const int dynLds = 96 * 512 * 2;   // 98304 B pinned keys slice
  static int attrSet = 0;
  if (!attrSet){
    hipFuncSetAttribute(reinterpret_cast<const void*>(dec_kernel),
                        hipFuncAttributeMaxDynamicSharedMemorySize, dynLds);
    attrSet = 1;
  }

  prep_kernel<<<dim3(416), dim3(256), 0, stream>>>(
      Wq, Wfc, Wihd, Whhd, Wihe, Whhe, Wk,
      Wq4, Wfc4, Wihd4, Whhd4, Wihe4, Whhe4, Wke4);
  enc_kernel<<<dim3(256), dim3(1024), 0, stream>>>(
      x, emb, Wihe4, Whhe4, bihe, bhhe, Wke4, enc, keysn, g_h, g_c);
  tr_kernel<<<dim3(8192), dim3(256), 0, stream>>>(keysn, keyst);
  dec_kernel<<<dim3(256), dim3(1024), dynLds, stream>>>(
      x, emb, Wq4, vv, Wihd4, Whhd4, bihd, bhhd,
      enc, keyst, g_h, g_c, h2_hist, out_h, out_c);
  fc_kernel<<<dim3(16384), dim3(256), 0, stream>>>(h2_hist, Wfc4, bfc, out_logits);
}